// Round 11
// baseline (330.676 us; speedup 1.0000x reference)
//
#include <hip/hip_runtime.h>

#define K_CODES 1024
#define DIM 128
#define HW 1024
#define NTOT 65536
#define DECAY 0.99f
#define OMD 0.01f
#define EPS 1e-5f
#define CCOEF 0.25f
#define MARGIN 1e-4f

// d_out offsets (floats)
#define OFF_Q    0
#define OFF_IDX  8388608
#define OFF_LOSS (8388608 + 65536)
#define OFF_EMB  (OFF_LOSS + 1)
#define OFF_ECS  (OFF_EMB + 131072)
#define OFF_EMAW (OFF_ECS + 1024)

typedef __attribute__((ext_vector_type(8))) short short8v;
typedef __attribute__((ext_vector_type(4))) float f32x4;

__device__ __forceinline__ unsigned short f2bf(float f) {
    unsigned u = __float_as_uint(f);
    u += 0x7fffu + ((u >> 16) & 1u);      // RNE to bf16 (inputs finite)
    return (unsigned short)(u >> 16);
}
__device__ __forceinline__ float bf2f(unsigned short h) {
    return __uint_as_float(((unsigned)h) << 16);
}

__global__ __launch_bounds__(256) void kzero(float* __restrict__ p, int n) {
    int i = blockIdx.x * 256 + threadIdx.x;
    if (i < n) p[i] = 0.f;
}

// numpy pairwise_sum replica (contiguous fp32, n=128, SSE nlanes=4) — verified.
__device__ __forceinline__ float np_pairwise_sumsq_128(const float* p, size_t stride) {
    float r[8][4];
    #pragma unroll
    for (int j = 0; j < 8; ++j)
        #pragma unroll
        for (int L = 0; L < 4; ++L) {
            float x = p[(size_t)(j * 4 + L) * stride];
            r[j][L] = __fmul_rn(x, x);
        }
    #pragma unroll
    for (int c = 1; c < 4; ++c)
        #pragma unroll
        for (int j = 0; j < 8; ++j)
            #pragma unroll
            for (int L = 0; L < 4; ++L) {
                float x = p[(size_t)(c * 32 + j * 4 + L) * stride];
                r[j][L] = __fadd_rn(r[j][L], __fmul_rn(x, x));
            }
    float V[4];
    #pragma unroll
    for (int L = 0; L < 4; ++L) {
        float a = __fadd_rn(r[0][L], r[1][L]);
        float b = __fadd_rn(r[2][L], r[3][L]);
        float c2 = __fadd_rn(r[4][L], r[5][L]);
        float d2 = __fadd_rn(r[6][L], r[7][L]);
        V[L] = __fadd_rn(__fadd_rn(a, b), __fadd_rn(c2, d2));
    }
    return __fadd_rn(__fadd_rn(V[0], V[1]), __fadd_rn(V[2], V[3]));
}

// LDS-transpose 128 rows of ze -> flat_c (coalesced) + nx per row (verified).
__global__ __launch_bounds__(256) void knx(const float* __restrict__ ze,
                                           float* __restrict__ nx,
                                           float* __restrict__ flat_c) {
    __shared__ float t[128][133];
    const int tid = threadIdx.x;
    const int n0 = blockIdx.x * 128;
    const int b = n0 >> 10, hw0 = n0 & (HW - 1);
    const float* zb = ze + (size_t)b * (DIM * HW) + hw0;
    #pragma unroll
    for (int i = 0; i < 64; ++i) {
        int d = i * 2 + (tid >> 7);
        int hw = tid & 127;
        t[hw][d] = zb[(size_t)d * HW + hw];
    }
    __syncthreads();
    if (tid < 128) nx[n0 + tid] = np_pairwise_sumsq_128(&t[tid][0], 1);
    if (flat_c) {
        #pragma unroll
        for (int i = 0; i < 16; ++i) {
            int lin = i * 256 + tid;
            int r  = lin >> 5;
            int c4 = lin & 31;
            float4 v = *(const float4*)&t[r][c4 * 4];
            *(float4*)&flat_c[(size_t)(n0 + r) * DIM + c4 * 4] = v;
        }
    }
}

// ne[k] (np-pairwise, verified) + bf16 hi/lo split of embed
__global__ __launch_bounds__(256) void knorm(const float* __restrict__ embed,
                                             float* __restrict__ norm2,
                                             unsigned short* __restrict__ eh_g,
                                             unsigned short* __restrict__ el_g) {
    int k = blockIdx.x * 256 + threadIdx.x;
    const float* row = embed + (size_t)k * DIM;
    norm2[k] = np_pairwise_sumsq_128(row, 1);
    if (eh_g) {
        #pragma unroll 8
        for (int d = 0; d < DIM; ++d) {
            float f = row[d];
            unsigned short h = f2bf(f);
            eh_g[(size_t)k * DIM + d] = h;
            el_g[(size_t)k * DIM + d] = f2bf(f - bf2f(h));
        }
    }
}

// bf16x3 MFMA single-pass argmin v4: NO LDS staging of e, NO barriers in the
// hot loop. e-fragments (eh/el) load straight from global (L2-resident 512KB)
// into registers, one subtile prefetched ahead. Per subtile (16 codes):
// 8x 16B loads + 24 MFMA + min-track. Same lane->element maps, same MFMA
// order, same score fold as verified r10 kernel -> bit-identical results.
// Per row tracks (min1,code1,min2); gap > MARGIN proves exact winner
// (skew bound ~4.7e-5 incl. tie guard); else row flagged for krefine.
__global__ __launch_bounds__(256, 2) void kapprox(
    const float* __restrict__ flat_c, const unsigned short* __restrict__ eh_g,
    const unsigned short* __restrict__ el_g, const float* __restrict__ norm2,
    int* __restrict__ idx_ws, float* __restrict__ idx_out,
    unsigned* __restrict__ hist, unsigned* __restrict__ flcnt,
    unsigned* __restrict__ fl_list)
{
    __shared__ float nes[1024];

    const int tid = threadIdx.x;
    const int l = tid & 63;
    const int w = tid >> 6;
    const int lg = l >> 4;        // 0..3
    const int lm = l & 15;
    const int n0 = blockIdx.x * 128;

    for (int i = tid; i < 1024; i += 256) nes[i] = norm2[i];

    // x-frags: rows n0 + w*32 + lm (group0) / +16 (group1); k = ks*32+lg*8+e
    short8v xh0[4], xl0[4], xh1[4], xl1[4];
    {
        const float* xr0 = flat_c + (size_t)(n0 + w * 32 + lm) * DIM;
        const float* xr1 = xr0 + 16 * DIM;
        #pragma unroll
        for (int ks = 0; ks < 4; ++ks) {
            int kb = ks * 32 + lg * 8;
            float f0[8], f1[8];
            *(float4*)&f0[0] = *(const float4*)(xr0 + kb);
            *(float4*)&f0[4] = *(const float4*)(xr0 + kb + 4);
            *(float4*)&f1[0] = *(const float4*)(xr1 + kb);
            *(float4*)&f1[4] = *(const float4*)(xr1 + kb + 4);
            #pragma unroll
            for (int e = 0; e < 8; ++e) {
                unsigned short h0 = f2bf(f0[e]);
                unsigned short h1 = f2bf(f1[e]);
                xh0[ks][e] = (short)h0;
                xl0[ks][e] = (short)f2bf(f0[e] - bf2f(h0));
                xh1[ks][e] = (short)h1;
                xl1[ks][e] = (short)f2bf(f1[e] - bf2f(h1));
            }
        }
    }
    __syncthreads();   // nes ready (only barrier in the kernel body)

    // e-fragment source: lane (lm,lg) reads e[code=st*16+lm][ks*32+lg*8 ..+8]
    const unsigned short* ebase_h = eh_g + (size_t)lm * 128 + lg * 8;
    const unsigned short* ebase_l = el_g + (size_t)lm * 128 + lg * 8;

    short8v ceh[4], cel[4], peh[4], pel[4];
    #pragma unroll
    for (int ks = 0; ks < 4; ++ks) {
        ceh[ks] = *(const short8v*)(ebase_h + ks * 32);
        cel[ks] = *(const short8v*)(ebase_l + ks * 32);
    }

    float m1_0 = 3.4e38f, m2_0 = 3.4e38f;
    float m1_1 = 3.4e38f, m2_1 = 3.4e38f;
    int c1_0 = 0, c1_1 = 0;

    for (int st = 0; st < 64; ++st) {
        if (st + 1 < 64) {
            const size_t nb = (size_t)(st + 1) * (16 * 128);
            #pragma unroll
            for (int ks = 0; ks < 4; ++ks) {
                peh[ks] = *(const short8v*)(ebase_h + nb + ks * 32);
                pel[ks] = *(const short8v*)(ebase_l + nb + ks * 32);
            }
        }
        f32x4 a0 = {0.f,0.f,0.f,0.f}, a1 = {0.f,0.f,0.f,0.f};
        #pragma unroll
        for (int ks = 0; ks < 4; ++ks) {
            a0 = __builtin_amdgcn_mfma_f32_16x16x32_bf16(ceh[ks], xh0[ks], a0, 0, 0, 0);
            a0 = __builtin_amdgcn_mfma_f32_16x16x32_bf16(cel[ks], xh0[ks], a0, 0, 0, 0);
            a0 = __builtin_amdgcn_mfma_f32_16x16x32_bf16(ceh[ks], xl0[ks], a0, 0, 0, 0);
            a1 = __builtin_amdgcn_mfma_f32_16x16x32_bf16(ceh[ks], xh1[ks], a1, 0, 0, 0);
            a1 = __builtin_amdgcn_mfma_f32_16x16x32_bf16(cel[ks], xh1[ks], a1, 0, 0, 0);
            a1 = __builtin_amdgcn_mfma_f32_16x16x32_bf16(ceh[ks], xl1[ks], a1, 0, 0, 0);
        }
        #pragma unroll
        for (int r = 0; r < 4; ++r) {
            int code = st * 16 + lg * 4 + r;
            float ne = nes[code];
            float s0 = ne - 2.f * a0[r];
            float s1 = ne - 2.f * a1[r];
            m2_0 = fminf(m2_0, fmaxf(m1_0, s0));
            if (s0 < m1_0) { m1_0 = s0; c1_0 = code; }
            m2_1 = fminf(m2_1, fmaxf(m1_1, s1));
            if (s1 < m1_1) { m1_1 = s1; c1_1 = code; }
        }
        #pragma unroll
        for (int ks = 0; ks < 4; ++ks) {
            ceh[ks] = peh[ks];
            cel[ks] = pel[ks];
        }
    }

    // merge (m1,c1,m2) across the 4 lg lanes (xor 16, then 32)
    #pragma unroll
    for (int mk = 16; mk <= 32; mk <<= 1) {
        float om1 = __shfl_xor(m1_0, mk, 64);
        int   oc1 = __shfl_xor(c1_0, mk, 64);
        float om2 = __shfl_xor(m2_0, mk, 64);
        m2_0 = fminf(fminf(m2_0, om2), fmaxf(m1_0, om1));
        if (om1 < m1_0 || (om1 == m1_0 && oc1 < c1_0)) { m1_0 = om1; c1_0 = oc1; }
        float pm1 = __shfl_xor(m1_1, mk, 64);
        int   pc1 = __shfl_xor(c1_1, mk, 64);
        float pm2 = __shfl_xor(m2_1, mk, 64);
        m2_1 = fminf(fminf(m2_1, pm2), fmaxf(m1_1, pm1));
        if (pm1 < m1_1 || (pm1 == m1_1 && pc1 < c1_1)) { m1_1 = pm1; c1_1 = pc1; }
    }
    if (lg == 0) {
        int n = n0 + w * 32 + lm;
        if (m2_0 - m1_0 > MARGIN) {
            idx_ws[n] = c1_0;
            idx_out[n] = (float)c1_0;
            atomicAdd(&hist[c1_0], 1u);
        } else {
            unsigned p = atomicAdd(flcnt, 1u);
            fl_list[p] = (unsigned)n;
        }
        n += 16;
        if (m2_1 - m1_1 > MARGIN) {
            idx_ws[n] = c1_1;
            idx_out[n] = (float)c1_1;
            atomicAdd(&hist[c1_1], 1u);
        } else {
            unsigned p = atomicAdd(flcnt, 1u);
            fl_list[p] = (unsigned)n;
        }
    }
}

// exact full-scan for flagged rows, v2 (verified r10): 16 rows/block; 16
// chunks of 64 codes staged coalesced into LDS; each thread computes 4 codes.
__global__ __launch_bounds__(256) void krefine(
    const float* __restrict__ flat_c, const float* __restrict__ embed,
    const float* __restrict__ norm2, const float* __restrict__ nxg,
    const unsigned* __restrict__ flcnt, const unsigned* __restrict__ fl_list,
    int* __restrict__ idx_ws, float* __restrict__ idx_out,
    unsigned* __restrict__ hist)
{
    __shared__ float ec[64 * 132];
    __shared__ float xrow[16][132];
    __shared__ float xnx[16];
    __shared__ int   rn[16];
    const int tid = threadIdx.x;
    const int row = tid >> 4;
    const int q = tid & 15;
    const unsigned nflag = flcnt[0];
    for (unsigned base = blockIdx.x * 16u; base < nflag; base += gridDim.x * 16u) {
        __syncthreads();
        if (tid < 16) {
            unsigned f = base + tid;
            int n = (f < nflag) ? (int)fl_list[f] : -1;
            rn[tid] = n;
            xnx[tid] = (n >= 0) ? nxg[n] : 0.f;
        }
        __syncthreads();
        #pragma unroll
        for (int j = 0; j < 8; ++j) {
            int slot = j * 256 + tid;
            int r = slot >> 7, d = slot & 127;
            int n = rn[r];
            xrow[r][d] = (n >= 0) ? flat_c[(size_t)n * DIM + d] : 0.f;
        }
        float bs = 3.4e38f;
        int bk = 1 << 30;
        const int nrow = rn[row];
        const float nx = xnx[row];
        for (int chunk = 0; chunk < 16; ++chunk) {
            __syncthreads();
            #pragma unroll
            for (int j = 0; j < 8; ++j) {
                int lin = j * 256 + tid;
                int c = lin >> 5, d4 = lin & 31;
                float4 v = *(const float4*)(embed + (size_t)(chunk * 64 + c) * DIM + d4 * 4);
                *(float4*)&ec[c * 132 + d4 * 4] = v;
            }
            __syncthreads();
            #pragma unroll
            for (int jj = 0; jj < 4; ++jj) {
                int cl = q + jj * 16;
                int k = chunk * 64 + cl;
                const float* ep = &ec[cl * 132];
                const float* xp = &xrow[row][0];
                float dot = 0.f;
                #pragma unroll
                for (int d4 = 0; d4 < 32; ++d4) {
                    float4 e4 = *(const float4*)(ep + d4 * 4);
                    float4 x4 = *(const float4*)(xp + d4 * 4);
                    dot = fmaf(x4.x, e4.x, dot);
                    dot = fmaf(x4.y, e4.y, dot);
                    dot = fmaf(x4.z, e4.z, dot);
                    dot = fmaf(x4.w, e4.w, dot);
                }
                float s = __fsub_rn(__fadd_rn(nx, norm2[k]), __fmul_rn(2.f, dot));
                if (s < bs || (s == bs && k < bk)) { bs = s; bk = k; }
            }
        }
        #pragma unroll
        for (int off = 8; off >= 1; off >>= 1) {
            float os = __shfl_xor(bs, off, 16);
            int   ok = __shfl_xor(bk, off, 16);
            if (os < bs || (os == bs && ok < bk)) { bs = os; bk = ok; }
        }
        if (q == 0 && nrow >= 0) {
            idx_ws[nrow] = bk;
            idx_out[nrow] = (float)bk;
            atomicAdd(&hist[bk], 1u);
        }
    }
}

// ---- fallback exact-GEMM argmin (verified path, used when ws too small) ----
__global__ __launch_bounds__(256, 2) void kargmin(
    const float* __restrict__ ze, const float* __restrict__ embed,
    const float* __restrict__ norm2, const float* __restrict__ nxg,
    int* __restrict__ idx_ws, float* __restrict__ idx_out,
    unsigned int* __restrict__ hist)
{
    __shared__ float xs[128 * 36];
    __shared__ float es[128 * 36];
    __shared__ float nxs[128];
    const int tid = threadIdx.x;
    const int tx = tid & 15, ty = tid >> 4;
    const int n0 = blockIdx.x * 128;
    const float* zbase = ze + (size_t)(n0 >> 10) * (DIM * HW) + (n0 & (HW - 1));
    if (tid < 128) nxs[tid] = nxg[n0 + tid];
    float minv[8];
    int   mini[8];
    #pragma unroll
    for (int i = 0; i < 8; ++i) { minv[i] = 3.4e38f; mini[i] = 0; }
    for (int kt = 0; kt < 8; ++kt) {
        float acc[8][8];
        #pragma unroll
        for (int i = 0; i < 8; ++i)
            #pragma unroll
            for (int j = 0; j < 8; ++j) acc[i][j] = 0.f;
        for (int dc = 0; dc < 4; ++dc) {
            __syncthreads();
            #pragma unroll
            for (int it = 0; it < 4; ++it) {
                int lin = it * 256 + tid;
                int r  = lin & 127;
                int gu = lin >> 7;
                const float* gp = zbase + (size_t)(dc * 32 + gu * 4) * HW + r;
                float4 v;
                v.x = gp[0]; v.y = gp[HW]; v.z = gp[2 * HW]; v.w = gp[3 * HW];
                *(float4*)&xs[r * 36 + gu * 4] = v;
            }
            #pragma unroll
            for (int it = 0; it < 4; ++it) {
                int lin = it * 256 + tid;
                int k  = lin >> 3;
                int gu = lin & 7;
                float4 v = *(const float4*)(embed + (size_t)(kt * 128 + k) * DIM + dc * 32 + gu * 4);
                *(float4*)&es[k * 36 + gu * 4] = v;
            }
            __syncthreads();
            #pragma unroll
            for (int g = 0; g < 8; ++g) {
                float4 xf[8];
                #pragma unroll
                for (int i = 0; i < 8; ++i)
                    xf[i] = *(const float4*)&xs[(ty + i * 16) * 36 + g * 4];
                #pragma unroll
                for (int j = 0; j < 8; ++j) {
                    float4 ef = *(const float4*)&es[(tx + j * 16) * 36 + g * 4];
                    #pragma unroll
                    for (int i = 0; i < 8; ++i) {
                        acc[i][j] = fmaf(xf[i].x, ef.x, acc[i][j]);
                        acc[i][j] = fmaf(xf[i].y, ef.y, acc[i][j]);
                        acc[i][j] = fmaf(xf[i].z, ef.z, acc[i][j]);
                        acc[i][j] = fmaf(xf[i].w, ef.w, acc[i][j]);
                    }
                }
            }
        }
        #pragma unroll
        for (int j = 0; j < 8; ++j) {
            int kg = kt * 128 + tx + j * 16;
            float nrm = norm2[kg];
            #pragma unroll
            for (int i = 0; i < 8; ++i) {
                float q = __fadd_rn(nxs[ty + i * 16], nrm);
                float t = __fmul_rn(2.f, acc[i][j]);
                float s = __fsub_rn(q, t);
                if (s < minv[i]) { minv[i] = s; mini[i] = kg; }
            }
        }
    }
    #pragma unroll
    for (int i = 0; i < 8; ++i) {
        float v = minv[i]; int ix = mini[i];
        #pragma unroll
        for (int off = 8; off >= 1; off >>= 1) {
            float v2 = __shfl_xor(v, off, 16);
            int   i2 = __shfl_xor(ix, off, 16);
            if (v2 < v || (v2 == v && i2 < ix)) { v = v2; ix = i2; }
        }
        if (tx == 0) {
            int n = n0 + ty + i * 16;
            idx_ws[n] = ix;
            idx_out[n] = (float)ix;
            atomicAdd(&hist[ix], 1u);
        }
    }
}

// gather quantized, transposed write, loss (+ optional atomic dw fallback)
__global__ __launch_bounds__(256) void kquant(
    const float* __restrict__ ze, const float* __restrict__ embed,
    const int* __restrict__ idx_ws, float* __restrict__ qout,
    float* __restrict__ dw_atomic, float* __restrict__ loss_acc)
{
    __shared__ float q[128 * 133];
    __shared__ int idxs[128];
    __shared__ float lsum[4];
    const int tid = threadIdx.x;
    const int n0 = blockIdx.x * 128;
    const int b = n0 >> 10;
    const int hw0 = n0 & (HW - 1);
    if (tid < 128) idxs[tid] = idx_ws[n0 + tid];
    __syncthreads();
    #pragma unroll
    for (int it = 0; it < 16; ++it) {
        int r = it * 8 + (tid >> 5);
        int c = tid & 31;
        float4 v = *(const float4*)(embed + (size_t)idxs[r] * DIM + c * 4);
        *(float4*)&q[r * 133 + c * 4] = v;
    }
    __syncthreads();
    const float* zb = ze + (size_t)b * (DIM * HW) + hw0;
    float* qb = qout + (size_t)b * (DIM * HW) + hw0;
    float lacc = 0.f;
    for (int dd = 0; dd < 64; ++dd) {
        int d = dd * 2 + (tid >> 7);
        int hw = tid & 127;
        float val = q[hw * 133 + d];
        size_t off = (size_t)d * HW + hw;
        float z = zb[off];
        qb[off] = val;
        float diff = val - z;
        lacc = fmaf(diff, diff, lacc);
        if (dw_atomic) atomicAdd(&dw_atomic[idxs[hw] * DIM + d], z);
    }
    #pragma unroll
    for (int off = 32; off >= 1; off >>= 1) lacc += __shfl_xor(lacc, off, 64);
    if ((tid & 63) == 0) lsum[tid >> 6] = lacc;
    __syncthreads();
    if (tid == 0) atomicAdd(loss_acc, lsum[0] + lsum[1] + lsum[2] + lsum[3]);
}

// deterministic segment-sum: block(8 waves)/code, waves scan n-ranges ascending
__global__ __launch_bounds__(512) void kdw(
    const int* __restrict__ idx_ws, const float* __restrict__ flat_c,
    float* __restrict__ dw)
{
    __shared__ float part[8][128];
    const int k = blockIdx.x;
    const int lane = threadIdx.x & 63;
    const int w = threadIdx.x >> 6;
    float lo = 0.f, hi = 0.f;
    const int nbeg = w * (NTOT / 8);
    const int nend = nbeg + (NTOT / 8);
    for (int base = nbeg; base < nend; base += 64) {
        int my = idx_ws[base + lane];
        unsigned long long m = __ballot(my == k);
        while (m) {
            int bit = __ffsll((long long)m) - 1;
            m &= m - 1;
            const float* row = flat_c + (size_t)(base + bit) * DIM;
            lo += row[lane];
            hi += row[lane + 64];
        }
    }
    part[w][lane] = lo;
    part[w][lane + 64] = hi;
    __syncthreads();
    if (w == 0) {
        float a = part[0][lane], b = part[0][lane + 64];
        #pragma unroll
        for (int u = 1; u < 8; ++u) {
            a += part[u][lane];
            b += part[u][lane + 64];
        }
        dw[k * DIM + lane] = a;
        dw[k * DIM + lane + 64] = b;
    }
}

__global__ __launch_bounds__(256) void kfin1(
    const unsigned int* __restrict__ hist, const float* __restrict__ ema_cs,
    float* __restrict__ out_ecs, float* __restrict__ rcp,
    float* __restrict__ loss_out, const float* __restrict__ loss_acc)
{
    const int tid = threadIdx.x;
    __shared__ float wsum[4];
    float local = 0.f;
    float necs[4];
    #pragma unroll
    for (int u = 0; u < 4; ++u) {
        int k = u * 256 + tid;
        necs[u] = DECAY * ema_cs[k] + OMD * (float)hist[k];
        out_ecs[k] = necs[u];
        local += necs[u];
    }
    #pragma unroll
    for (int off = 32; off >= 1; off >>= 1) local += __shfl_xor(local, off, 64);
    if ((tid & 63) == 0) wsum[tid >> 6] = local;
    __syncthreads();
    float ntot = wsum[0] + wsum[1] + wsum[2] + wsum[3];
    #pragma unroll
    for (int u = 0; u < 4; ++u) {
        int k = u * 256 + tid;
        float cs = (necs[u] + EPS) / (ntot + (float)K_CODES * EPS) * ntot;
        rcp[k] = 1.f / cs;
    }
    if (tid == 0) loss_out[0] = loss_acc[0] * (CCOEF / (float)((size_t)NTOT * DIM));
}

__global__ __launch_bounds__(256) void kfin2(
    const float* __restrict__ ema_w, const float* __restrict__ dw,
    const float* __restrict__ rcp, float* __restrict__ out_emb,
    float* __restrict__ out_emaw)
{
    int e = blockIdx.x * 256 + threadIdx.x;
    int k = e >> 7;
    float nw = DECAY * ema_w[e] + OMD * dw[e];
    out_emaw[e] = nw;
    out_emb[e] = nw * rcp[k];
}

extern "C" void kernel_launch(void* const* d_in, const int* in_sizes, int n_in,
                              void* d_out, int out_size, void* d_ws, size_t ws_size,
                              hipStream_t stream) {
    const float* ze     = (const float*)d_in[0];
    const float* embed  = (const float*)d_in[1];
    const float* ema_cs = (const float*)d_in[2];
    const float* ema_w  = (const float*)d_in[3];
    float* out = (float*)d_out;

    // ws layout (words), NO aliases (kapprox writes idx while eh still live):
    // hist/loss/flcnt/fl_list/dw contiguous so one kzero covers accumulators.
    float* ws = (float*)d_ws;
    float*          ws_norm2 = ws;                                   // 1024
    float*          ws_rcp   = ws + 1024;                            // 1024
    int*            ws_idx   = (int*)(ws + 2048);                    // 65536
    unsigned*       ws_hist  = (unsigned*)(ws + 67584);              // 1024
    float*          ws_loss  = ws + 68608;                           // 1
    unsigned*       ws_flcnt = (unsigned*)(ws + 68609);              // 1 (+2 pad)
    unsigned*       ws_fl    = (unsigned*)(ws + 68612);              // 65536
    float*          ws_dw    = ws + 134148;                          // 131072
    unsigned short* ws_eh    = (unsigned short*)(ws + 265220);       // 65536 words
    unsigned short* ws_el    = (unsigned short*)(ws + 330756);       // 65536 words
    float*          ws_nx    = ws + 396292;                          // 65536
    float*          ws_flat  = ws + 461828;                          // 8388608
    const size_t need = (size_t)8850436 * sizeof(float);
    const bool big_ws = ws_size >= need;

    if (big_ws) {
        // zero hist + loss + flcnt (contiguous 1026 words)
        hipLaunchKernelGGL(kzero, dim3(5), dim3(256), 0, stream, (float*)ws_hist, 1026);
        hipLaunchKernelGGL(knx, dim3(512), dim3(256), 0, stream, ze, ws_nx, ws_flat);
        hipLaunchKernelGGL(knorm, dim3(4), dim3(256), 0, stream, embed, ws_norm2, ws_eh, ws_el);
        hipLaunchKernelGGL(kapprox, dim3(512), dim3(256), 0, stream,
                           ws_flat, ws_eh, ws_el, ws_norm2,
                           ws_idx, out + OFF_IDX, ws_hist, ws_flcnt, ws_fl);
        hipLaunchKernelGGL(krefine, dim3(512), dim3(256), 0, stream,
                           ws_flat, embed, ws_norm2, ws_nx, ws_flcnt, ws_fl,
                           ws_idx, out + OFF_IDX, ws_hist);
        hipLaunchKernelGGL(kquant, dim3(512), dim3(256), 0, stream,
                           ze, embed, ws_idx, out + OFF_Q, (float*)nullptr, ws_loss);
        hipLaunchKernelGGL(kdw, dim3(1024), dim3(512), 0, stream,
                           ws_idx, ws_flat, ws_dw);
    } else {
        // fallback: verified exact path with atomic dw
        hipLaunchKernelGGL(kzero, dim3(773), dim3(256), 0, stream, (float*)ws_hist, 197636);
        hipLaunchKernelGGL(knx, dim3(512), dim3(256), 0, stream, ze, ws_nx, (float*)nullptr);
        hipLaunchKernelGGL(knorm, dim3(4), dim3(256), 0, stream, embed, ws_norm2,
                           (unsigned short*)nullptr, (unsigned short*)nullptr);
        hipLaunchKernelGGL(kargmin, dim3(512), dim3(256), 0, stream,
                           ze, embed, ws_norm2, ws_nx, ws_idx, out + OFF_IDX, ws_hist);
        hipLaunchKernelGGL(kquant, dim3(512), dim3(256), 0, stream,
                           ze, embed, ws_idx, out + OFF_Q, ws_dw, ws_loss);
    }
    hipLaunchKernelGGL(kfin1, dim3(1), dim3(256), 0, stream,
                       ws_hist, ema_cs, out + OFF_ECS, ws_rcp, out + OFF_LOSS, ws_loss);
    hipLaunchKernelGGL(kfin2, dim3(512), dim3(256), 0, stream,
                       ema_w, ws_dw, ws_rcp, out + OFF_EMB, out + OFF_EMAW);
}

// Round 12
// 213.968 us; speedup vs baseline: 1.5454x; 1.5454x over previous
//
#include <hip/hip_runtime.h>

#define K_CODES 1024
#define DIM 128
#define HW 1024
#define NTOT 65536
#define DECAY 0.99f
#define OMD 0.01f
#define EPS 1e-5f
#define CCOEF 0.25f
#define MARGIN 1e-4f

// d_out offsets (floats)
#define OFF_Q    0
#define OFF_IDX  8388608
#define OFF_LOSS (8388608 + 65536)
#define OFF_EMB  (OFF_LOSS + 1)
#define OFF_ECS  (OFF_EMB + 131072)
#define OFF_EMAW (OFF_ECS + 1024)

typedef __attribute__((ext_vector_type(8))) short short8v;
typedef __attribute__((ext_vector_type(4))) float f32x4;

__device__ __forceinline__ unsigned short f2bf(float f) {
    unsigned u = __float_as_uint(f);
    u += 0x7fffu + ((u >> 16) & 1u);      // RNE to bf16 (inputs finite)
    return (unsigned short)(u >> 16);
}
__device__ __forceinline__ float bf2f(unsigned short h) {
    return __uint_as_float(((unsigned)h) << 16);
}

__global__ __launch_bounds__(256) void kzero(float* __restrict__ p, int n) {
    int i = blockIdx.x * 256 + threadIdx.x;
    if (i < n) p[i] = 0.f;
}

// numpy pairwise_sum replica (contiguous fp32, n=128, SSE nlanes=4) — verified.
__device__ __forceinline__ float np_pairwise_sumsq_128(const float* p, size_t stride) {
    float r[8][4];
    #pragma unroll
    for (int j = 0; j < 8; ++j)
        #pragma unroll
        for (int L = 0; L < 4; ++L) {
            float x = p[(size_t)(j * 4 + L) * stride];
            r[j][L] = __fmul_rn(x, x);
        }
    #pragma unroll
    for (int c = 1; c < 4; ++c)
        #pragma unroll
        for (int j = 0; j < 8; ++j)
            #pragma unroll
            for (int L = 0; L < 4; ++L) {
                float x = p[(size_t)(c * 32 + j * 4 + L) * stride];
                r[j][L] = __fadd_rn(r[j][L], __fmul_rn(x, x));
            }
    float V[4];
    #pragma unroll
    for (int L = 0; L < 4; ++L) {
        float a = __fadd_rn(r[0][L], r[1][L]);
        float b = __fadd_rn(r[2][L], r[3][L]);
        float c2 = __fadd_rn(r[4][L], r[5][L]);
        float d2 = __fadd_rn(r[6][L], r[7][L]);
        V[L] = __fadd_rn(__fadd_rn(a, b), __fadd_rn(c2, d2));
    }
    return __fadd_rn(__fadd_rn(V[0], V[1]), __fadd_rn(V[2], V[3]));
}

// LDS-transpose 128 rows of ze -> flat_c (coalesced) + nx per row (verified).
__global__ __launch_bounds__(256) void knx(const float* __restrict__ ze,
                                           float* __restrict__ nx,
                                           float* __restrict__ flat_c) {
    __shared__ float t[128][133];
    const int tid = threadIdx.x;
    const int n0 = blockIdx.x * 128;
    const int b = n0 >> 10, hw0 = n0 & (HW - 1);
    const float* zb = ze + (size_t)b * (DIM * HW) + hw0;
    #pragma unroll
    for (int i = 0; i < 64; ++i) {
        int d = i * 2 + (tid >> 7);
        int hw = tid & 127;
        t[hw][d] = zb[(size_t)d * HW + hw];
    }
    __syncthreads();
    if (tid < 128) nx[n0 + tid] = np_pairwise_sumsq_128(&t[tid][0], 1);
    if (flat_c) {
        #pragma unroll
        for (int i = 0; i < 16; ++i) {
            int lin = i * 256 + tid;
            int r  = lin >> 5;
            int c4 = lin & 31;
            float4 v = *(const float4*)&t[r][c4 * 4];
            *(float4*)&flat_c[(size_t)(n0 + r) * DIM + c4 * 4] = v;
        }
    }
}

// ne[k] (np-pairwise, verified) + bf16 hi/lo split of embed
__global__ __launch_bounds__(256) void knorm(const float* __restrict__ embed,
                                             float* __restrict__ norm2,
                                             unsigned short* __restrict__ eh_g,
                                             unsigned short* __restrict__ el_g) {
    int k = blockIdx.x * 256 + threadIdx.x;
    const float* row = embed + (size_t)k * DIM;
    norm2[k] = np_pairwise_sumsq_128(row, 1);
    if (eh_g) {
        #pragma unroll 8
        for (int d = 0; d < DIM; ++d) {
            float f = row[d];
            unsigned short h = f2bf(f);
            eh_g[(size_t)k * DIM + d] = h;
            el_g[(size_t)k * DIM + d] = f2bf(f - bf2f(h));
        }
    }
}

// bf16x3 MFMA prefilter (r8-verified). Block: 128 rows x 1024 codes, 4 waves,
// 32 codes/iter (2 subtiles), XOR-swizzled LDS (bank-conflict-free), 64 iters:
// pass 1 (it 0..31) row-min; pass 2 (it 32..63) bit-identical recompute,
// collect codes with s~ <= min + MARGIN (cap 8; P(>8 within margin) ~ 0).
__global__ __launch_bounds__(256, 2) void kapprox(
    const float* __restrict__ flat_c, const unsigned short* __restrict__ eh_g,
    const unsigned short* __restrict__ el_g, const float* __restrict__ norm2,
    unsigned* __restrict__ cnt_g, unsigned* __restrict__ cand_g)
{
    __shared__ __align__(16) unsigned short ehs[2][32 * 128];
    __shared__ __align__(16) unsigned short els[2][32 * 128];
    __shared__ float nes[1024];
    __shared__ unsigned ccnt[128];
    __shared__ unsigned ccode[128][8];

    const int tid = threadIdx.x;
    const int l = tid & 63;
    const int w = tid >> 6;
    const int lg = l >> 4;        // 0..3
    const int lm = l & 15;
    const int n0 = blockIdx.x * 128;

    for (int i = tid; i < 1024; i += 256) nes[i] = norm2[i];
    if (tid < 128) ccnt[tid] = 0;

    // x-frags once: rows n0 + w*32 + lm (group0) / +16 (group1); k = ks*32+lg*8+e
    short8v xh0[4], xl0[4], xh1[4], xl1[4];
    {
        const float* xr0 = flat_c + (size_t)(n0 + w * 32 + lm) * DIM;
        const float* xr1 = xr0 + 16 * DIM;
        #pragma unroll
        for (int ks = 0; ks < 4; ++ks) {
            int kb = ks * 32 + lg * 8;
            float f0[8], f1[8];
            *(float4*)&f0[0] = *(const float4*)(xr0 + kb);
            *(float4*)&f0[4] = *(const float4*)(xr0 + kb + 4);
            *(float4*)&f1[0] = *(const float4*)(xr1 + kb);
            *(float4*)&f1[4] = *(const float4*)(xr1 + kb + 4);
            #pragma unroll
            for (int e = 0; e < 8; ++e) {
                unsigned short h0 = f2bf(f0[e]);
                unsigned short h1 = f2bf(f1[e]);
                xh0[ks][e] = (short)h0;
                xl0[ks][e] = (short)f2bf(f0[e] - bf2f(h0));
                xh1[ks][e] = (short)h1;
                xl1[ks][e] = (short)f2bf(f1[e] - bf2f(h1));
            }
        }
    }

    // staging positions: code = tid>>4 (+16), granule = tid&15, XOR swizzle
    const int c0g = tid >> 4;
    const int g0  = tid & 15;
    const int c1g = 16 + c0g;
    const int so0 = c0g * 128 + ((g0 ^ (c0g & 15)) * 8);
    const int so1 = c1g * 128 + ((g0 ^ (c1g & 15)) * 8);
    const size_t gsrc0 = (size_t)c0g * 128 + g0 * 8;
    const size_t gsrc1 = (size_t)c1g * 128 + g0 * 8;

    int roff[4];
    #pragma unroll
    for (int ks = 0; ks < 4; ++ks)
        roff[ks] = lm * 128 + (((ks * 4 + lg) ^ lm) * 8);

    uint4 peh0 = *(const uint4*)(eh_g + gsrc0);
    uint4 peh1 = *(const uint4*)(eh_g + gsrc1);
    uint4 pel0 = *(const uint4*)(el_g + gsrc0);
    uint4 pel1 = *(const uint4*)(el_g + gsrc1);
    *(uint4*)&ehs[0][so0] = peh0;
    *(uint4*)&ehs[0][so1] = peh1;
    *(uint4*)&els[0][so0] = pel0;
    *(uint4*)&els[0][so1] = pel1;
    __syncthreads();

    float rmin0 = 3.4e38f, rmin1 = 3.4e38f, thr0 = 0.f, thr1 = 0.f;

    for (int it = 0; it < 64; ++it) {
        const int ct = it & 31;
        const int buf = it & 1;
        if (it == 32) {
            rmin0 = fminf(rmin0, __shfl_xor(rmin0, 16, 64));
            rmin0 = fminf(rmin0, __shfl_xor(rmin0, 32, 64));
            rmin1 = fminf(rmin1, __shfl_xor(rmin1, 16, 64));
            rmin1 = fminf(rmin1, __shfl_xor(rmin1, 32, 64));
            thr0 = rmin0 + MARGIN;
            thr1 = rmin1 + MARGIN;
        }
        const int nt = it + 1;
        if (nt < 64) {
            const size_t nb = (size_t)(nt & 31) * (32 * 128);
            peh0 = *(const uint4*)(eh_g + nb + gsrc0);
            peh1 = *(const uint4*)(eh_g + nb + gsrc1);
            pel0 = *(const uint4*)(el_g + nb + gsrc0);
            pel1 = *(const uint4*)(el_g + nb + gsrc1);
        }
        f32x4 a00 = {0.f,0.f,0.f,0.f}, a01 = {0.f,0.f,0.f,0.f};
        f32x4 a10 = {0.f,0.f,0.f,0.f}, a11 = {0.f,0.f,0.f,0.f};
        const unsigned short* be = &ehs[buf][0];
        const unsigned short* bl = &els[buf][0];
        #pragma unroll
        for (int ks = 0; ks < 4; ++ks) {
            short8v eA = *(const short8v*)(be + roff[ks]);
            short8v lA = *(const short8v*)(bl + roff[ks]);
            short8v eB = *(const short8v*)(be + 2048 + roff[ks]);
            short8v lB = *(const short8v*)(bl + 2048 + roff[ks]);
            a00 = __builtin_amdgcn_mfma_f32_16x16x32_bf16(eA, xh0[ks], a00, 0, 0, 0);
            a00 = __builtin_amdgcn_mfma_f32_16x16x32_bf16(lA, xh0[ks], a00, 0, 0, 0);
            a00 = __builtin_amdgcn_mfma_f32_16x16x32_bf16(eA, xl0[ks], a00, 0, 0, 0);
            a10 = __builtin_amdgcn_mfma_f32_16x16x32_bf16(eA, xh1[ks], a10, 0, 0, 0);
            a10 = __builtin_amdgcn_mfma_f32_16x16x32_bf16(lA, xh1[ks], a10, 0, 0, 0);
            a10 = __builtin_amdgcn_mfma_f32_16x16x32_bf16(eA, xl1[ks], a10, 0, 0, 0);
            a01 = __builtin_amdgcn_mfma_f32_16x16x32_bf16(eB, xh0[ks], a01, 0, 0, 0);
            a01 = __builtin_amdgcn_mfma_f32_16x16x32_bf16(lB, xh0[ks], a01, 0, 0, 0);
            a01 = __builtin_amdgcn_mfma_f32_16x16x32_bf16(eB, xl0[ks], a01, 0, 0, 0);
            a11 = __builtin_amdgcn_mfma_f32_16x16x32_bf16(eB, xh1[ks], a11, 0, 0, 0);
            a11 = __builtin_amdgcn_mfma_f32_16x16x32_bf16(lB, xh1[ks], a11, 0, 0, 0);
            a11 = __builtin_amdgcn_mfma_f32_16x16x32_bf16(eB, xl1[ks], a11, 0, 0, 0);
        }
        #pragma unroll
        for (int r = 0; r < 4; ++r) {
            int code0 = ct * 32 + lg * 4 + r;
            int code1 = code0 + 16;
            float ne0 = nes[code0];
            float ne1 = nes[code1];
            float s00 = ne0 - 2.f * a00[r];
            float s01 = ne1 - 2.f * a01[r];
            float s10 = ne0 - 2.f * a10[r];
            float s11 = ne1 - 2.f * a11[r];
            if (it < 32) {
                rmin0 = fminf(fminf(s00, s01), rmin0);
                rmin1 = fminf(fminf(s10, s11), rmin1);
            } else {
                if (s00 <= thr0) {
                    unsigned p = atomicAdd(&ccnt[w * 32 + lm], 1u);
                    if (p < 8) ccode[w * 32 + lm][p] = (unsigned)code0;
                }
                if (s01 <= thr0) {
                    unsigned p = atomicAdd(&ccnt[w * 32 + lm], 1u);
                    if (p < 8) ccode[w * 32 + lm][p] = (unsigned)code1;
                }
                if (s10 <= thr1) {
                    unsigned p = atomicAdd(&ccnt[w * 32 + 16 + lm], 1u);
                    if (p < 8) ccode[w * 32 + 16 + lm][p] = (unsigned)code0;
                }
                if (s11 <= thr1) {
                    unsigned p = atomicAdd(&ccnt[w * 32 + 16 + lm], 1u);
                    if (p < 8) ccode[w * 32 + 16 + lm][p] = (unsigned)code1;
                }
            }
        }
        if (nt < 64) {
            *(uint4*)&ehs[buf ^ 1][so0] = peh0;
            *(uint4*)&ehs[buf ^ 1][so1] = peh1;
            *(uint4*)&els[buf ^ 1][so0] = pel0;
            *(uint4*)&els[buf ^ 1][so1] = pel1;
        }
        __syncthreads();
    }

    if (tid < 128) {
        unsigned r = tid, n = n0 + tid;
        cnt_g[n] = min(ccnt[r], 8u);
        uint4 pk;
        pk.x = (ccode[r][0] & 0xffffu) | ((ccode[r][1] & 0xffffu) << 16);
        pk.y = (ccode[r][2] & 0xffffu) | ((ccode[r][3] & 0xffffu) << 16);
        pk.z = (ccode[r][4] & 0xffffu) | ((ccode[r][5] & 0xffffu) << 16);
        pk.w = (ccode[r][6] & 0xffffu) | ((ccode[r][7] & 0xffffu) << 16);
        *(uint4*)(cand_g + (size_t)n * 4) = pk;
    }
}

// exact rescore: thread/row; vectorized float4 loads, same ascending fmaf
// chain + rounding pipeline as verified kargmin; lowest-k tie-break.
__global__ __launch_bounds__(256) void krescore(
    const float* __restrict__ flat_c, const float* __restrict__ embed,
    const float* __restrict__ norm2, const float* __restrict__ nxg,
    const unsigned* __restrict__ cnt_g, const unsigned* __restrict__ cand_g,
    int* __restrict__ idx_ws, float* __restrict__ idx_out,
    unsigned* __restrict__ hist)
{
    const int n = blockIdx.x * 256 + threadIdx.x;
    const unsigned c = cnt_g[n];
    uint4 pk = *(const uint4*)(cand_g + (size_t)n * 4);
    int cc[8];
    cc[0] = pk.x & 0xffff; cc[1] = (pk.x >> 16) & 0xffff;
    cc[2] = pk.y & 0xffff; cc[3] = (pk.y >> 16) & 0xffff;
    cc[4] = pk.z & 0xffff; cc[5] = (pk.z >> 16) & 0xffff;
    cc[6] = pk.w & 0xffff; cc[7] = (pk.w >> 16) & 0xffff;
    int bestk = cc[0];
    if (c > 1) {
        float bests = 3.4e38f;
        bestk = 1 << 30;
        const float* xr = flat_c + (size_t)n * DIM;
        const float nx = nxg[n];
        #pragma unroll
        for (int q = 0; q < 8; ++q) {
            if (q < (int)c) {
                int k = cc[q];
                const float* er = embed + (size_t)k * DIM;
                float dot = 0.f;
                #pragma unroll
                for (int d4 = 0; d4 < 32; ++d4) {
                    float4 e4 = *(const float4*)(er + d4 * 4);
                    float4 x4 = *(const float4*)(xr + d4 * 4);
                    dot = fmaf(x4.x, e4.x, dot);
                    dot = fmaf(x4.y, e4.y, dot);
                    dot = fmaf(x4.z, e4.z, dot);
                    dot = fmaf(x4.w, e4.w, dot);
                }
                float qv = __fadd_rn(nx, norm2[k]);
                float s = __fsub_rn(qv, __fmul_rn(2.f, dot));
                if (s < bests || (s == bests && k < bestk)) { bests = s; bestk = k; }
            }
        }
    }
    idx_ws[n] = bestk;
    idx_out[n] = (float)bestk;
    atomicAdd(&hist[bestk], 1u);
}

// ---- fallback exact-GEMM argmin (verified path, used when ws too small) ----
__global__ __launch_bounds__(256, 2) void kargmin(
    const float* __restrict__ ze, const float* __restrict__ embed,
    const float* __restrict__ norm2, const float* __restrict__ nxg,
    int* __restrict__ idx_ws, float* __restrict__ idx_out,
    unsigned int* __restrict__ hist)
{
    __shared__ float xs[128 * 36];
    __shared__ float es[128 * 36];
    __shared__ float nxs[128];
    const int tid = threadIdx.x;
    const int tx = tid & 15, ty = tid >> 4;
    const int n0 = blockIdx.x * 128;
    const float* zbase = ze + (size_t)(n0 >> 10) * (DIM * HW) + (n0 & (HW - 1));
    if (tid < 128) nxs[tid] = nxg[n0 + tid];
    float minv[8];
    int   mini[8];
    #pragma unroll
    for (int i = 0; i < 8; ++i) { minv[i] = 3.4e38f; mini[i] = 0; }
    for (int kt = 0; kt < 8; ++kt) {
        float acc[8][8];
        #pragma unroll
        for (int i = 0; i < 8; ++i)
            #pragma unroll
            for (int j = 0; j < 8; ++j) acc[i][j] = 0.f;
        for (int dc = 0; dc < 4; ++dc) {
            __syncthreads();
            #pragma unroll
            for (int it = 0; it < 4; ++it) {
                int lin = it * 256 + tid;
                int r  = lin & 127;
                int gu = lin >> 7;
                const float* gp = zbase + (size_t)(dc * 32 + gu * 4) * HW + r;
                float4 v;
                v.x = gp[0]; v.y = gp[HW]; v.z = gp[2 * HW]; v.w = gp[3 * HW];
                *(float4*)&xs[r * 36 + gu * 4] = v;
            }
            #pragma unroll
            for (int it = 0; it < 4; ++it) {
                int lin = it * 256 + tid;
                int k  = lin >> 3;
                int gu = lin & 7;
                float4 v = *(const float4*)(embed + (size_t)(kt * 128 + k) * DIM + dc * 32 + gu * 4);
                *(float4*)&es[k * 36 + gu * 4] = v;
            }
            __syncthreads();
            #pragma unroll
            for (int g = 0; g < 8; ++g) {
                float4 xf[8];
                #pragma unroll
                for (int i = 0; i < 8; ++i)
                    xf[i] = *(const float4*)&xs[(ty + i * 16) * 36 + g * 4];
                #pragma unroll
                for (int j = 0; j < 8; ++j) {
                    float4 ef = *(const float4*)&es[(tx + j * 16) * 36 + g * 4];
                    #pragma unroll
                    for (int i = 0; i < 8; ++i) {
                        acc[i][j] = fmaf(xf[i].x, ef.x, acc[i][j]);
                        acc[i][j] = fmaf(xf[i].y, ef.y, acc[i][j]);
                        acc[i][j] = fmaf(xf[i].z, ef.z, acc[i][j]);
                        acc[i][j] = fmaf(xf[i].w, ef.w, acc[i][j]);
                    }
                }
            }
        }
        #pragma unroll
        for (int j = 0; j < 8; ++j) {
            int kg = kt * 128 + tx + j * 16;
            float nrm = norm2[kg];
            #pragma unroll
            for (int i = 0; i < 8; ++i) {
                float q = __fadd_rn(nxs[ty + i * 16], nrm);
                float t = __fmul_rn(2.f, acc[i][j]);
                float s = __fsub_rn(q, t);
                if (s < minv[i]) { minv[i] = s; mini[i] = kg; }
            }
        }
    }
    #pragma unroll
    for (int i = 0; i < 8; ++i) {
        float v = minv[i]; int ix = mini[i];
        #pragma unroll
        for (int off = 8; off >= 1; off >>= 1) {
            float v2 = __shfl_xor(v, off, 16);
            int   i2 = __shfl_xor(ix, off, 16);
            if (v2 < v || (v2 == v && i2 < ix)) { v = v2; ix = i2; }
        }
        if (tx == 0) {
            int n = n0 + ty + i * 16;
            idx_ws[n] = ix;
            idx_out[n] = (float)ix;
            atomicAdd(&hist[ix], 1u);
        }
    }
}

// gather quantized, transposed write, loss (+ optional atomic dw fallback)
__global__ __launch_bounds__(256) void kquant(
    const float* __restrict__ ze, const float* __restrict__ embed,
    const int* __restrict__ idx_ws, float* __restrict__ qout,
    float* __restrict__ dw_atomic, float* __restrict__ loss_acc)
{
    __shared__ float q[128 * 133];
    __shared__ int idxs[128];
    __shared__ float lsum[4];
    const int tid = threadIdx.x;
    const int n0 = blockIdx.x * 128;
    const int b = n0 >> 10;
    const int hw0 = n0 & (HW - 1);
    if (tid < 128) idxs[tid] = idx_ws[n0 + tid];
    __syncthreads();
    #pragma unroll
    for (int it = 0; it < 16; ++it) {
        int r = it * 8 + (tid >> 5);
        int c = tid & 31;
        float4 v = *(const float4*)(embed + (size_t)idxs[r] * DIM + c * 4);
        *(float4*)&q[r * 133 + c * 4] = v;
    }
    __syncthreads();
    const float* zb = ze + (size_t)b * (DIM * HW) + hw0;
    float* qb = qout + (size_t)b * (DIM * HW) + hw0;
    float lacc = 0.f;
    for (int dd = 0; dd < 64; ++dd) {
        int d = dd * 2 + (tid >> 7);
        int hw = tid & 127;
        float val = q[hw * 133 + d];
        size_t off = (size_t)d * HW + hw;
        float z = zb[off];
        qb[off] = val;
        float diff = val - z;
        lacc = fmaf(diff, diff, lacc);
        if (dw_atomic) atomicAdd(&dw_atomic[idxs[hw] * DIM + d], z);
    }
    #pragma unroll
    for (int off = 32; off >= 1; off >>= 1) lacc += __shfl_xor(lacc, off, 64);
    if ((tid & 63) == 0) lsum[tid >> 6] = lacc;
    __syncthreads();
    if (tid == 0) atomicAdd(loss_acc, lsum[0] + lsum[1] + lsum[2] + lsum[3]);
}

// deterministic segment-sum FUSED with EMA-w/embed finalize: block(8 waves)
// per code; waves scan n-ranges ascending; fixed wave-order combine; then
// nw = decay*ema_w + 0.01*dw, out_emaw, out_emb = nw*rcp[k]. Same summation
// order as the verified kdw+kfin2 pair.
__global__ __launch_bounds__(512) void kdwf(
    const int* __restrict__ idx_ws, const float* __restrict__ flat_c,
    const float* __restrict__ ema_w, const float* __restrict__ rcp,
    float* __restrict__ out_emb, float* __restrict__ out_emaw)
{
    __shared__ float part[8][128];
    const int k = blockIdx.x;
    const int lane = threadIdx.x & 63;
    const int w = threadIdx.x >> 6;
    float lo = 0.f, hi = 0.f;
    const int nbeg = w * (NTOT / 8);
    const int nend = nbeg + (NTOT / 8);
    for (int base = nbeg; base < nend; base += 64) {
        int my = idx_ws[base + lane];
        unsigned long long m = __ballot(my == k);
        while (m) {
            int bit = __ffsll((long long)m) - 1;
            m &= m - 1;
            const float* row = flat_c + (size_t)(base + bit) * DIM;
            lo += row[lane];
            hi += row[lane + 64];
        }
    }
    part[w][lane] = lo;
    part[w][lane + 64] = hi;
    __syncthreads();
    if (w == 0) {
        float a = part[0][lane], b = part[0][lane + 64];
        #pragma unroll
        for (int u = 1; u < 8; ++u) {
            a += part[u][lane];
            b += part[u][lane + 64];
        }
        const float r = rcp[k];
        int elo = k * DIM + lane, ehi = elo + 64;
        float nwa = DECAY * ema_w[elo] + OMD * a;
        float nwb = DECAY * ema_w[ehi] + OMD * b;
        out_emaw[elo] = nwa;
        out_emaw[ehi] = nwb;
        out_emb[elo] = nwa * r;
        out_emb[ehi] = nwb * r;
    }
}

__global__ __launch_bounds__(256) void kfin1(
    const unsigned int* __restrict__ hist, const float* __restrict__ ema_cs,
    float* __restrict__ out_ecs, float* __restrict__ rcp,
    float* __restrict__ loss_out, const float* __restrict__ loss_acc)
{
    const int tid = threadIdx.x;
    __shared__ float wsum[4];
    float local = 0.f;
    float necs[4];
    #pragma unroll
    for (int u = 0; u < 4; ++u) {
        int k = u * 256 + tid;
        necs[u] = DECAY * ema_cs[k] + OMD * (float)hist[k];
        out_ecs[k] = necs[u];
        local += necs[u];
    }
    #pragma unroll
    for (int off = 32; off >= 1; off >>= 1) local += __shfl_xor(local, off, 64);
    if ((tid & 63) == 0) wsum[tid >> 6] = local;
    __syncthreads();
    float ntot = wsum[0] + wsum[1] + wsum[2] + wsum[3];
    #pragma unroll
    for (int u = 0; u < 4; ++u) {
        int k = u * 256 + tid;
        float cs = (necs[u] + EPS) / (ntot + (float)K_CODES * EPS) * ntot;
        rcp[k] = 1.f / cs;
    }
    if (tid == 0) loss_out[0] = loss_acc[0] * (CCOEF / (float)((size_t)NTOT * DIM));
}

// fallback-only finalize from dw buffer
__global__ __launch_bounds__(256) void kfin2(
    const float* __restrict__ ema_w, const float* __restrict__ dw,
    const float* __restrict__ rcp, float* __restrict__ out_emb,
    float* __restrict__ out_emaw)
{
    int e = blockIdx.x * 256 + threadIdx.x;
    int k = e >> 7;
    float nw = DECAY * ema_w[e] + OMD * dw[e];
    out_emaw[e] = nw;
    out_emb[e] = nw * rcp[k];
}

extern "C" void kernel_launch(void* const* d_in, const int* in_sizes, int n_in,
                              void* d_out, int out_size, void* d_ws, size_t ws_size,
                              hipStream_t stream) {
    const float* ze     = (const float*)d_in[0];
    const float* embed  = (const float*)d_in[1];
    const float* ema_cs = (const float*)d_in[2];
    const float* ema_w  = (const float*)d_in[3];
    float* out = (float*)d_out;

    // ws layout (words). Aliases (disjoint lifetimes):
    //   eh over idx (eh dead before krescore writes idx)
    //   cand over dw-region (cand dead before fallback dw use; big path never writes dw)
    float* ws = (float*)d_ws;
    float*          ws_norm2 = ws;                                   // 1024
    float*          ws_rcp   = ws + 1024;                            // 1024
    int*            ws_idx   = (int*)(ws + 2048);                    // 65536
    unsigned short* ws_eh    = (unsigned short*)(ws + 2048);         // alias
    unsigned*       ws_hist  = (unsigned*)(ws + 67584);              // 1024
    float*          ws_loss  = ws + 68608;                           // 1 (+3 pad)
    unsigned*       ws_cnt   = (unsigned*)(ws + 68612);              // 65536
    float*          ws_dw    = ws + 134148;                          // 131072 (region 262144)
    unsigned*       ws_cand  = (unsigned*)(ws + 134148);             // alias, 262144
    float*          ws_nx    = ws + 396292;                          // 65536
    float*          ws_flat  = ws + 461828;                          // 8388608
    unsigned short* ws_el    = (unsigned short*)(ws + 8850436);      // 65536 words
    const size_t need = (size_t)(8850436 + 65536) * sizeof(float);
    const bool big_ws = ws_size >= need;

    if (big_ws) {
        // zero hist (1024) + loss (1); dw fully written by kdwf epilogue
        hipLaunchKernelGGL(kzero, dim3(5), dim3(256), 0, stream, (float*)ws_hist, 1025);
        hipLaunchKernelGGL(knx, dim3(512), dim3(256), 0, stream, ze, ws_nx, ws_flat);
        hipLaunchKernelGGL(knorm, dim3(4), dim3(256), 0, stream, embed, ws_norm2, ws_eh, ws_el);
        hipLaunchKernelGGL(kapprox, dim3(512), dim3(256), 0, stream,
                           ws_flat, ws_eh, ws_el, ws_norm2, ws_cnt, ws_cand);
        hipLaunchKernelGGL(krescore, dim3(256), dim3(256), 0, stream,
                           ws_flat, embed, ws_norm2, ws_nx, ws_cnt, ws_cand,
                           ws_idx, out + OFF_IDX, ws_hist);
        hipLaunchKernelGGL(kquant, dim3(512), dim3(256), 0, stream,
                           ze, embed, ws_idx, out + OFF_Q, (float*)nullptr, ws_loss);
        hipLaunchKernelGGL(kfin1, dim3(1), dim3(256), 0, stream,
                           ws_hist, ema_cs, out + OFF_ECS, ws_rcp, out + OFF_LOSS, ws_loss);
        hipLaunchKernelGGL(kdwf, dim3(1024), dim3(512), 0, stream,
                           ws_idx, ws_flat, ema_w, ws_rcp,
                           out + OFF_EMB, out + OFF_EMAW);
    } else {
        // fallback: verified exact path with atomic dw
        hipLaunchKernelGGL(kzero, dim3(773), dim3(256), 0, stream, (float*)ws_hist, 197636);
        hipLaunchKernelGGL(knx, dim3(512), dim3(256), 0, stream, ze, ws_nx, (float*)nullptr);
        hipLaunchKernelGGL(knorm, dim3(4), dim3(256), 0, stream, embed, ws_norm2,
                           (unsigned short*)nullptr, (unsigned short*)nullptr);
        hipLaunchKernelGGL(kargmin, dim3(512), dim3(256), 0, stream,
                           ze, embed, ws_norm2, ws_nx, ws_idx, out + OFF_IDX, ws_hist);
        hipLaunchKernelGGL(kquant, dim3(512), dim3(256), 0, stream,
                           ze, embed, ws_idx, out + OFF_Q, ws_dw, ws_loss);
        hipLaunchKernelGGL(kfin1, dim3(1), dim3(256), 0, stream,
                           ws_hist, ema_cs, out + OFF_ECS, ws_rcp, out + OFF_LOSS, ws_loss);
        hipLaunchKernelGGL(kfin2, dim3(512), dim3(256), 0, stream,
                           ema_w, ws_dw, ws_rcp, out + OFF_EMB, out + OFF_EMAW);
    }
}